// Round 6
// baseline (2260.138 us; speedup 1.0000x reference)
//
#include <hip/hip_runtime.h>

typedef __attribute__((ext_vector_type(8))) short short8;
typedef __attribute__((ext_vector_type(4))) float f32x4;

#define IMH 2048
#define IMW 2048
#define NB 2
#define NL 3
#define NT 4
#define HS 512
#define OV2 32
#define PH 128

#define PSTRIDE 272           // ushorts per LDS row: 544 B
#define PATCH_ROWS 96         // 95 rows staged per 32-q chunk; 96*272*2 = 52224 B
#define NDI 10                // distinct B fragments per q (fixed by 128-row PSF)

__device__ __forceinline__ ushort f2bf(float f) {
  unsigned u = __float_as_uint(f);
  return (ushort)((u + 0x7FFFu + ((u >> 16) & 1u)) >> 16);
}

// J16[b][r][c] = bf16(target[b][0][r][2047-c])
__global__ void build_J16(const float* __restrict__ tgt, ushort* __restrict__ J16) {
  int idx = blockIdx.x * 256 + threadIdx.x;
  if (idx >= NB * IMH * IMW) return;
  int c = idx & (IMW - 1);
  int r = (idx >> 11) & (IMH - 1);
  int b = idx >> 22;
  J16[idx] = f2bf(tgt[((size_t)(b * IMH) + r) * IMW + (IMW - 1 - c)]);
}

// Bfrag[pf][q][di][lane] (short8): n=lane&15, h=lane>>4; elem i -> k=8h+i;
// value = psf_rot[p,q], p = 16*di + n - 8h - i; psf_rot[p,q] = psfs[l][tj*4+ti][q][127-p]
__global__ void build_Bfrag(const float* __restrict__ psfs, uint4* __restrict__ Bf) {
  int idx = blockIdx.x * 256 + threadIdx.x;
  if (idx >= 48 * 128 * NDI * 64) return;
  int ln = idx & 63;
  int di = (idx >> 6) % NDI;
  int q  = (idx / (64 * NDI)) & 127;
  int pf = idx / (64 * NDI * 128);
  int tj = pf & 3, ti = (pf >> 2) & 3, l = pf >> 4;
  const float* col = psfs + ((size_t)((l * 16 + tj * 4 + ti) * PH + q)) * PH;
  int n = ln & 15, h = ln >> 4;
  int p0 = 16 * di + n - 8 * h;
  ushort v[8];
  #pragma unroll
  for (int i = 0; i < 8; ++i) {
    int p = p0 - i;
    v[i] = (p >= 0 && p < PH) ? f2bf(col[PH - 1 - p]) : (ushort)0;
  }
  uint4 o;
  o.x = (unsigned)v[0] | ((unsigned)v[1] << 16);
  o.y = (unsigned)v[2] | ((unsigned)v[3] << 16);
  o.z = (unsigned)v[4] | ((unsigned)v[5] << 16);
  o.w = (unsigned)v[6] | ((unsigned)v[7] << 16);
  Bf[idx] = o;
}

#define MFMA16(a, bfr, c) __builtin_amdgcn_mfma_f32_16x16x32_bf16((a), (bfr), (c), 0, 0, 0)
#define SBAR() __builtin_amdgcn_sched_barrier(0)

// 3 blocks/CU with single-buffer operand rotation (B[10]+AP[4]+AH[4]).
// XCD-grouped tiling: xcd = blockIdx.x & 7 (dispatch id % 8); each XCD owns
// 2 whole 512x512 tiles per z -> B slices stay in that XCD's L2.
__global__ __launch_bounds__(256, 3)
void conv_mfma(const ushort* __restrict__ J16, const short8* __restrict__ Bfrag,
               float* __restrict__ out) {
  __shared__ __align__(16) ushort patch[PATCH_ROWS * PSTRIDE];   // 52224 B

  const int tid  = threadIdx.x;
  const int lane = tid & 63;
  const int xs   = tid >> 6;      // wave id = x-subtile
  const int n    = lane & 15;
  const int hq   = lane >> 4;

  // XCD-grouped work assignment (bijective):
  const int c  = blockIdx.x & 7;                        // = dispatch%8 = XCD
  const int g  = (c << 1) | (blockIdx.y >> 3);          // tile 0..15
  const int wi = (blockIdx.x >> 3) | ((blockIdx.y & 7) << 2);  // 0..31 in tile
  const int x0 = ((((g & 3) << 3) + (wi & 7)) << 6);    // 64-wide in x
  const int y0 = ((((g >> 2) << 2) + (wi >> 3)) << 7);  // 128-wide in y
  const int bl = blockIdx.z;
  const int b = bl / NL, l = bl - NL * b;

  const int tylo = (y0 > OV2 ? (y0 - OV2) : 0) / HS;
  const int tyhi = min(NT - 1, (y0 + 127 + OV2) / HS);
  const int txlo = (x0 > OV2 ? (x0 - OV2) : 0) / HS;
  const int txhi = min(NT - 1, (x0 + 63 + OV2) / HS);

  f32x4 facc[8] = {};

  for (int ti = tylo; ti <= tyhi; ++ti) {
    const int h0 = max(0, ti * HS - OV2);
    const int h1 = min(IMH, (ti + 1) * HS + OV2);
    // valid s-pair range: pair sp covers out cols [y0+32sp, y0+32sp+31]
    const int splo = max(0, (h0 - y0) / 32);
    const int sphi = min(3, (h1 - 1 - y0) / 32);
    const bool fullS = (splo == 0) & (sphi == 3);
    for (int tj = txlo; tj <= txhi; ++tj) {
      const int w0 = max(0, tj * HS - OV2);
      const int w1 = min(IMW, (tj + 1) * HS + OV2);

      const short8* __restrict__ Bt =
          Bfrag + (size_t)((l * 4 + ti) * 4 + tj) * (128 * NDI * 64) + lane;

      // per-wave valid q range: keep q iff some A row lands in [w0,w1)
      const int xw = x0 + (xs << 4);
      const int qminw = xw + 65 - w1;
      const int qmaxw = xw + 79 - w0;

      f32x4 acc[8] = {};

      #pragma unroll 1
      for (int qlo = 0; qlo < 128; qlo += 32) {
        const int rrlo = 97 - qlo;     // rows staged: 95; image row rg = x0+(xs<<4)+n+64-q
        __syncthreads();
        // stage 95 rows x 32 16B-chunks; chunk-granular clip; XOR swizzle
        const int rbase = x0 - 64 + rrlo;
        const int cbase = y0 - 64;
        #pragma unroll 4
        for (int item = tid; item < 95 * 32; item += 256) {
          const int slot = item >> 5;
          const int cc   = item & 31;
          const int rg   = rbase + slot;
          const int cg   = cbase + (cc << 3);
          uint4 v = {0u, 0u, 0u, 0u};
          if (rg >= w0 && rg < w1 && cg >= h0 && (cg + 8) <= h1)
            v = *(const uint4*)(J16 + ((size_t)b << 22) + ((size_t)rg << 11) + cg);
          *(uint4*)&patch[slot * PSTRIDE + (((cc ^ (slot & 3))) << 3)] = v;
        }
        __syncthreads();

        // per-wave clip of this 32-q chunk
        int s2 = qminw - qlo; if (s2 < 0) s2 = 0;
        int e2 = qmaxw - qlo + 1; if (e2 > 32) e2 = 32;
        if (s2 >= e2) continue;            // no barriers skipped: counts stay uniform

        const int sbase = (xs << 4) + n + 128 - rrlo;   // = 16*xs + n + 31 + qlo

        short8 B[NDI], AP[4];

        // prologue: B(q0) and AP(q0)
        const int q0 = qlo + s2;
        {
          const short8* __restrict__ Bp0 = Bt + (size_t)q0 * (NDI * 64);
          #pragma unroll
          for (int d = 0; d < NDI; ++d) B[d] = Bp0[d << 6];
          const int row0 = sbase - q0;     // in [0,94]
          const ushort* __restrict__ ar0 =
              patch + row0 * PSTRIDE + ((hq ^ (row0 & 3)) << 3);
          AP[0] = *(const short8*)(ar0);
          AP[1] = *(const short8*)(ar0 + 32);
          AP[2] = *(const short8*)(ar0 + 64);
          AP[3] = *(const short8*)(ar0 + 96);
        }

        // Rotation: B pair {2d,2d+1} last consumed at k=4-d, refilled right after
        // -> 32-MFMA prefetch distance, single buffer. AP refilled after k=3.
        auto qstepF = [&](int q, int qn) {
          const int row = sbase - q;
          const ushort* __restrict__ ar =
              patch + row * PSTRIDE + ((hq ^ (row & 3)) << 3);
          short8 AH[4];
          AH[0] = *(const short8*)(ar + 128);
          AH[1] = *(const short8*)(ar + 160);
          AH[2] = *(const short8*)(ar + 192);
          AH[3] = *(const short8*)(ar + 224);
          const short8* __restrict__ Bp = Bt + (size_t)qn * (NDI * 64);
          int rowp = sbase - qn; if (rowp < 0) rowp = 0;   // clamp: value unused
          const ushort* __restrict__ arp =
              patch + rowp * PSTRIDE + ((hq ^ (rowp & 3)) << 3);
          SBAR();
          // k=0: d=8,9
          acc[0] = MFMA16(AP[0], B[8], acc[0]);
          acc[1] = MFMA16(AP[0], B[9], acc[1]);
          acc[2] = MFMA16(AP[1], B[8], acc[2]);
          acc[3] = MFMA16(AP[1], B[9], acc[3]);
          acc[4] = MFMA16(AP[2], B[8], acc[4]);
          acc[5] = MFMA16(AP[2], B[9], acc[5]);
          acc[6] = MFMA16(AP[3], B[8], acc[6]);
          acc[7] = MFMA16(AP[3], B[9], acc[7]);
          SBAR();
          B[8] = Bp[8 << 6]; B[9] = Bp[9 << 6];
          SBAR();
          // k=1: d=6,7
          acc[0] = MFMA16(AP[1], B[6], acc[0]);
          acc[1] = MFMA16(AP[1], B[7], acc[1]);
          acc[2] = MFMA16(AP[2], B[6], acc[2]);
          acc[3] = MFMA16(AP[2], B[7], acc[3]);
          acc[4] = MFMA16(AP[3], B[6], acc[4]);
          acc[5] = MFMA16(AP[3], B[7], acc[5]);
          acc[6] = MFMA16(AH[0], B[6], acc[6]);
          acc[7] = MFMA16(AH[0], B[7], acc[7]);
          SBAR();
          B[6] = Bp[6 << 6]; B[7] = Bp[7 << 6];
          SBAR();
          // k=2: d=4,5
          acc[0] = MFMA16(AP[2], B[4], acc[0]);
          acc[1] = MFMA16(AP[2], B[5], acc[1]);
          acc[2] = MFMA16(AP[3], B[4], acc[2]);
          acc[3] = MFMA16(AP[3], B[5], acc[3]);
          acc[4] = MFMA16(AH[0], B[4], acc[4]);
          acc[5] = MFMA16(AH[0], B[5], acc[5]);
          acc[6] = MFMA16(AH[1], B[4], acc[6]);
          acc[7] = MFMA16(AH[1], B[5], acc[7]);
          SBAR();
          B[4] = Bp[4 << 6]; B[5] = Bp[5 << 6];
          SBAR();
          // k=3: d=2,3 (last AP use)
          acc[0] = MFMA16(AP[3], B[2], acc[0]);
          acc[1] = MFMA16(AP[3], B[3], acc[1]);
          acc[2] = MFMA16(AH[0], B[2], acc[2]);
          acc[3] = MFMA16(AH[0], B[3], acc[3]);
          acc[4] = MFMA16(AH[1], B[2], acc[4]);
          acc[5] = MFMA16(AH[1], B[3], acc[5]);
          acc[6] = MFMA16(AH[2], B[2], acc[6]);
          acc[7] = MFMA16(AH[2], B[3], acc[7]);
          SBAR();
          B[2] = Bp[2 << 6]; B[3] = Bp[3 << 6];
          AP[0] = *(const short8*)(arp);
          AP[1] = *(const short8*)(arp + 32);
          AP[2] = *(const short8*)(arp + 64);
          AP[3] = *(const short8*)(arp + 96);
          SBAR();
          // k=4: d=0,1 (AH only)
          acc[0] = MFMA16(AH[0], B[0], acc[0]);
          acc[1] = MFMA16(AH[0], B[1], acc[1]);
          acc[2] = MFMA16(AH[1], B[0], acc[2]);
          acc[3] = MFMA16(AH[1], B[1], acc[3]);
          acc[4] = MFMA16(AH[2], B[0], acc[4]);
          acc[5] = MFMA16(AH[2], B[1], acc[5]);
          acc[6] = MFMA16(AH[3], B[0], acc[6]);
          acc[7] = MFMA16(AH[3], B[1], acc[7]);
          SBAR();
          B[0] = Bp[0 << 6]; B[1] = Bp[1 << 6];
          SBAR();
        };

        // partial-S variant: skip MFMAs for s-pairs outside [splo,sphi]
        // (their wy window weight is 0; acc stays 0 -> exact). Uniform branches.
        auto qstepP = [&](int q, int qn) {
          const int row = sbase - q;
          const ushort* __restrict__ ar =
              patch + row * PSTRIDE + ((hq ^ (row & 3)) << 3);
          short8 AH[4];
          AH[0] = *(const short8*)(ar + 128);
          AH[1] = *(const short8*)(ar + 160);
          AH[2] = *(const short8*)(ar + 192);
          AH[3] = *(const short8*)(ar + 224);
          const short8* __restrict__ Bp = Bt + (size_t)qn * (NDI * 64);
          int rowp = sbase - qn; if (rowp < 0) rowp = 0;
          const ushort* __restrict__ arp =
              patch + rowp * PSTRIDE + ((hq ^ (rowp & 3)) << 3);
          SBAR();
          #pragma unroll
          for (int k = 0; k < 5; ++k) {
            if (splo <= 0 && 0 <= sphi) {
              const short8 Aj = (k < 4) ? AP[k] : AH[k - 4];
              acc[0] = MFMA16(Aj, B[8 - (k << 1)], acc[0]);
              acc[1] = MFMA16(Aj, B[9 - (k << 1)], acc[1]);
            }
            if (splo <= 1 && 1 <= sphi) {
              const short8 Aj = (1 + k < 4) ? AP[1 + k] : AH[k - 3];
              acc[2] = MFMA16(Aj, B[8 - (k << 1)], acc[2]);
              acc[3] = MFMA16(Aj, B[9 - (k << 1)], acc[3]);
            }
            if (splo <= 2 && 2 <= sphi) {
              const short8 Aj = (2 + k < 4) ? AP[2 + k] : AH[k - 2];
              acc[4] = MFMA16(Aj, B[8 - (k << 1)], acc[4]);
              acc[5] = MFMA16(Aj, B[9 - (k << 1)], acc[5]);
            }
            if (splo <= 3 && 3 <= sphi) {
              const short8 Aj = (3 + k < 4) ? AP[3 + k] : AH[k - 1];
              acc[6] = MFMA16(Aj, B[8 - (k << 1)], acc[6]);
              acc[7] = MFMA16(Aj, B[9 - (k << 1)], acc[7]);
            }
            // rotation refills (unconditional, keep prefetch chain intact)
            B[8 - (k << 1)] = Bp[(8 - (k << 1)) << 6];
            B[9 - (k << 1)] = Bp[(9 - (k << 1)) << 6];
            if (k == 3) {
              AP[0] = *(const short8*)(arp);
              AP[1] = *(const short8*)(arp + 32);
              AP[2] = *(const short8*)(arp + 64);
              AP[3] = *(const short8*)(arp + 96);
            }
            SBAR();
          }
        };

        if (fullS) {
          #pragma unroll 1
          for (int q2 = s2; q2 < e2; ++q2) {
            const int q = qlo + q2;
            qstepF(q, min(q + 1, 127));
          }
        } else {
          #pragma unroll 1
          for (int q2 = s2; q2 < e2; ++q2) {
            const int q = qlo + q2;
            qstepP(q, min(q + 1, 127));
          }
        }
      }

      // apply window for this tile (acc -> facc); norm recomputed in epilogue
      const int Sh = h1 - h0, Sw = w1 - w0;
      const float sig = 0.25f * (float)min(Sh, Sw);
      const float c2 = 0.5f / (sig * sig);
      const float stepy = (float)Sh / (float)(Sh - 1);
      const float stepx = (float)Sw / (float)(Sw - 1);
      float wx[4];
      #pragma unroll
      for (int r = 0; r < 4; ++r) {
        const int x = x0 + (xs << 4) + (hq << 2) + r;
        const float xv = -0.5f * (float)Sw + (float)(x - w0) * stepx;
        wx[r] = (x >= w0 && x < w1) ? __expf(-xv * xv * c2) : 0.0f;
      }
      #pragma unroll
      for (int s = 0; s < 8; ++s) {
        const int y = y0 + (s << 4) + n;
        const float yv = -0.5f * (float)Sh + (float)(y - h0) * stepy;
        const float wy = (y >= h0 && y < h1) ? __expf(-yv * yv * c2) : 0.0f;
        #pragma unroll
        for (int r = 0; r < 4; ++r) facc[s][r] += wy * wx[r] * acc[s][r];
      }
    }
  }

  // epilogue: recompute norm analytically, store out[b,l,x,2047-y]
  f32x4 nacc[8] = {};
  for (int ti = tylo; ti <= tyhi; ++ti) {
    const int h0 = max(0, ti * HS - OV2);
    const int h1 = min(IMH, (ti + 1) * HS + OV2);
    for (int tj = txlo; tj <= txhi; ++tj) {
      const int w0 = max(0, tj * HS - OV2);
      const int w1 = min(IMW, (tj + 1) * HS + OV2);
      const int Sh = h1 - h0, Sw = w1 - w0;
      const float sig = 0.25f * (float)min(Sh, Sw);
      const float c2 = 0.5f / (sig * sig);
      const float stepy = (float)Sh / (float)(Sh - 1);
      const float stepx = (float)Sw / (float)(Sw - 1);
      float wx[4];
      #pragma unroll
      for (int r = 0; r < 4; ++r) {
        const int x = x0 + (xs << 4) + (hq << 2) + r;
        const float xv = -0.5f * (float)Sw + (float)(x - w0) * stepx;
        wx[r] = (x >= w0 && x < w1) ? __expf(-xv * xv * c2) : 0.0f;
      }
      #pragma unroll
      for (int s = 0; s < 8; ++s) {
        const int y = y0 + (s << 4) + n;
        const float yv = -0.5f * (float)Sh + (float)(y - h0) * stepy;
        const float wy = (y >= h0 && y < h1) ? __expf(-yv * yv * c2) : 0.0f;
        #pragma unroll
        for (int r = 0; r < 4; ++r) nacc[s][r] += wy * wx[r];
      }
    }
  }
  #pragma unroll
  for (int s = 0; s < 8; ++s) {
    const int y = y0 + (s << 4) + n;
    #pragma unroll
    for (int r = 0; r < 4; ++r) {
      const int x = x0 + (xs << 4) + (hq << 2) + r;
      out[(((size_t)(b * NL + l) << 11) + x) * IMW + (IMW - 1 - y)] =
          facc[s][r] / fmaxf(nacc[s][r], 1e-12f);
    }
  }
}

extern "C" void kernel_launch(void* const* d_in, const int* in_sizes, int n_in,
                              void* d_out, int out_size, void* d_ws, size_t ws_size,
                              hipStream_t stream) {
  const float* tgt  = (const float*)d_in[0];
  const float* psfs = (const float*)d_in[1];
  ushort* J16 = (ushort*)d_ws;                                       // 16.8 MB
  short8* Bf  = (short8*)((char*)d_ws + (size_t)NB * IMH * IMW * 2); // 62.9 MB
  float* o = (float*)d_out;

  build_J16<<<dim3((NB * IMH * IMW + 255) / 256), 256, 0, stream>>>(tgt, J16);
  build_Bfrag<<<dim3((48 * 128 * NDI * 64 + 255) / 256), 256, 0, stream>>>(
      psfs, (uint4*)Bf);
  conv_mfma<<<dim3(32, 16, NB * NL), 256, 0, stream>>>(J16, Bf, o);
}

// Round 8
// 1372.345 us; speedup vs baseline: 1.6469x; 1.6469x over previous
//
#include <hip/hip_runtime.h>

typedef __attribute__((ext_vector_type(8))) short short8;
typedef __attribute__((ext_vector_type(4))) float f32x4;

#define IMH 2048
#define IMW 2048
#define NB 2
#define NL 3
#define NT 4
#define HS 512
#define OV2 32
#define PH 128

#define PSTRIDE 272           // ushorts per LDS row: 544 B
#define PATCH_ROWS 96         // 95 rows staged per 32-q chunk; 96*272*2 = 52224 B
#define NDI 10                // distinct B fragments per q (fixed by 128-row PSF)

__device__ __forceinline__ ushort f2bf(float f) {
  unsigned u = __float_as_uint(f);
  return (ushort)((u + 0x7FFFu + ((u >> 16) & 1u)) >> 16);
}

// J16[b][r][c] = bf16(target[b][0][r][2047-c])
__global__ void build_J16(const float* __restrict__ tgt, ushort* __restrict__ J16) {
  int idx = blockIdx.x * 256 + threadIdx.x;
  if (idx >= NB * IMH * IMW) return;
  int c = idx & (IMW - 1);
  int r = (idx >> 11) & (IMH - 1);
  int b = idx >> 22;
  J16[idx] = f2bf(tgt[((size_t)(b * IMH) + r) * IMW + (IMW - 1 - c)]);
}

// Bfrag[pf][q][di][lane] (short8): n=lane&15, h=lane>>4; elem i -> k=8h+i;
// value = psf_rot[p,q], p = 16*di + n - 8h - i; psf_rot[p,q] = psfs[l][tj*4+ti][q][127-p]
__global__ void build_Bfrag(const float* __restrict__ psfs, uint4* __restrict__ Bf) {
  int idx = blockIdx.x * 256 + threadIdx.x;
  if (idx >= 48 * 128 * NDI * 64) return;
  int ln = idx & 63;
  int di = (idx >> 6) % NDI;
  int q  = (idx / (64 * NDI)) & 127;
  int pf = idx / (64 * NDI * 128);
  int tj = pf & 3, ti = (pf >> 2) & 3, l = pf >> 4;
  const float* col = psfs + ((size_t)((l * 16 + tj * 4 + ti) * PH + q)) * PH;
  int n = ln & 15, h = ln >> 4;
  int p0 = 16 * di + n - 8 * h;
  ushort v[8];
  #pragma unroll
  for (int i = 0; i < 8; ++i) {
    int p = p0 - i;
    v[i] = (p >= 0 && p < PH) ? f2bf(col[PH - 1 - p]) : (ushort)0;
  }
  uint4 o;
  o.x = (unsigned)v[0] | ((unsigned)v[1] << 16);
  o.y = (unsigned)v[2] | ((unsigned)v[3] << 16);
  o.z = (unsigned)v[4] | ((unsigned)v[5] << 16);
  o.w = (unsigned)v[6] | ((unsigned)v[7] << 16);
  Bf[idx] = o;
}

#define MFMA16(a, bfr, c) __builtin_amdgcn_mfma_f32_16x16x32_bf16((a), (bfr), (c), 0, 0, 0)
#define SBAR() __builtin_amdgcn_sched_barrier(0)

// Round-5 inner loop (single qstepF path, proven 84 VGPR / no-spill) +
// XCD-grouped tiling only: xcd = blockIdx.x & 7 = dispatch%8; each XCD owns
// 2 whole 512x512 tiles per z -> B slices stay in that XCD's L2 (FETCH -31%).
__global__ __launch_bounds__(256, 3)
void conv_mfma(const ushort* __restrict__ J16, const short8* __restrict__ Bfrag,
               float* __restrict__ out) {
  __shared__ __align__(16) ushort patch[PATCH_ROWS * PSTRIDE];   // 52224 B

  const int tid  = threadIdx.x;
  const int lane = tid & 63;
  const int xs   = tid >> 6;      // wave id = x-subtile
  const int n    = lane & 15;
  const int hq   = lane >> 4;

  // XCD-grouped work assignment (bijective):
  const int c  = blockIdx.x & 7;                        // = dispatch%8 = XCD
  const int g  = (c << 1) | (blockIdx.y >> 3);          // tile 0..15
  const int wi = (blockIdx.x >> 3) | ((blockIdx.y & 7) << 2);  // 0..31 in tile
  const int x0 = ((((g & 3) << 3) + (wi & 7)) << 6);    // 64-wide in x
  const int y0 = ((((g >> 2) << 2) + (wi >> 3)) << 7);  // 128-wide in y
  const int bl = blockIdx.z;
  const int b = bl / NL, l = bl - NL * b;

  const int tylo = (y0 > OV2 ? (y0 - OV2) : 0) / HS;
  const int tyhi = min(NT - 1, (y0 + 127 + OV2) / HS);
  const int txlo = (x0 > OV2 ? (x0 - OV2) : 0) / HS;
  const int txhi = min(NT - 1, (x0 + 63 + OV2) / HS);

  f32x4 facc[8] = {};

  for (int ti = tylo; ti <= tyhi; ++ti) {
    const int h0 = max(0, ti * HS - OV2);
    const int h1 = min(IMH, (ti + 1) * HS + OV2);
    for (int tj = txlo; tj <= txhi; ++tj) {
      const int w0 = max(0, tj * HS - OV2);
      const int w1 = min(IMW, (tj + 1) * HS + OV2);

      const short8* __restrict__ Bt =
          Bfrag + (size_t)((l * 4 + ti) * 4 + tj) * (128 * NDI * 64) + lane;

      // per-wave valid q range: keep q iff some A row lands in [w0,w1)
      const int xw = x0 + (xs << 4);
      const int qminw = xw + 65 - w1;
      const int qmaxw = xw + 79 - w0;

      f32x4 acc[8] = {};

      #pragma unroll 1
      for (int qlo = 0; qlo < 128; qlo += 32) {
        const int rrlo = 97 - qlo;     // rows staged: 95; image row rg = x0+(xs<<4)+n+64-q
        __syncthreads();
        // stage 95 rows x 32 16B-chunks; chunk-granular clip; XOR swizzle
        const int rbase = x0 - 64 + rrlo;
        const int cbase = y0 - 64;
        #pragma unroll 4
        for (int item = tid; item < 95 * 32; item += 256) {
          const int slot = item >> 5;
          const int cc   = item & 31;
          const int rg   = rbase + slot;
          const int cg   = cbase + (cc << 3);
          uint4 v = {0u, 0u, 0u, 0u};
          if (rg >= w0 && rg < w1 && cg >= h0 && (cg + 8) <= h1)
            v = *(const uint4*)(J16 + ((size_t)b << 22) + ((size_t)rg << 11) + cg);
          *(uint4*)&patch[slot * PSTRIDE + (((cc ^ (slot & 3))) << 3)] = v;
        }
        __syncthreads();

        // per-wave clip of this 32-q chunk
        int s2 = qminw - qlo; if (s2 < 0) s2 = 0;
        int e2 = qmaxw - qlo + 1; if (e2 > 32) e2 = 32;
        if (s2 >= e2) continue;            // no barriers skipped: counts stay uniform

        const int sbase = (xs << 4) + n + 128 - rrlo;   // = 16*xs + n + 31 + qlo

        short8 B[NDI], AP[4];

        // prologue: B(q0) and AP(q0)
        const int q0 = qlo + s2;
        {
          const short8* __restrict__ Bp0 = Bt + (size_t)q0 * (NDI * 64);
          #pragma unroll
          for (int d = 0; d < NDI; ++d) B[d] = Bp0[d << 6];
          const int row0 = sbase - q0;     // in [0,94]
          const ushort* __restrict__ ar0 =
              patch + row0 * PSTRIDE + ((hq ^ (row0 & 3)) << 3);
          AP[0] = *(const short8*)(ar0);
          AP[1] = *(const short8*)(ar0 + 32);
          AP[2] = *(const short8*)(ar0 + 64);
          AP[3] = *(const short8*)(ar0 + 96);
        }

        // Rotation: B pair {2d,2d+1} last consumed at k=4-d, refilled right after
        // -> 32-MFMA prefetch distance, single buffer. AP refilled after k=3.
        auto qstep = [&](int q, int qn) {
          const int row = sbase - q;
          const ushort* __restrict__ ar =
              patch + row * PSTRIDE + ((hq ^ (row & 3)) << 3);
          short8 AH[4];
          AH[0] = *(const short8*)(ar + 128);
          AH[1] = *(const short8*)(ar + 160);
          AH[2] = *(const short8*)(ar + 192);
          AH[3] = *(const short8*)(ar + 224);
          const short8* __restrict__ Bp = Bt + (size_t)qn * (NDI * 64);
          int rowp = sbase - qn; if (rowp < 0) rowp = 0;   // clamp: value unused
          const ushort* __restrict__ arp =
              patch + rowp * PSTRIDE + ((hq ^ (rowp & 3)) << 3);
          SBAR();
          // k=0: d=8,9
          acc[0] = MFMA16(AP[0], B[8], acc[0]);
          acc[1] = MFMA16(AP[0], B[9], acc[1]);
          acc[2] = MFMA16(AP[1], B[8], acc[2]);
          acc[3] = MFMA16(AP[1], B[9], acc[3]);
          acc[4] = MFMA16(AP[2], B[8], acc[4]);
          acc[5] = MFMA16(AP[2], B[9], acc[5]);
          acc[6] = MFMA16(AP[3], B[8], acc[6]);
          acc[7] = MFMA16(AP[3], B[9], acc[7]);
          SBAR();
          B[8] = Bp[8 << 6]; B[9] = Bp[9 << 6];
          SBAR();
          // k=1: d=6,7
          acc[0] = MFMA16(AP[1], B[6], acc[0]);
          acc[1] = MFMA16(AP[1], B[7], acc[1]);
          acc[2] = MFMA16(AP[2], B[6], acc[2]);
          acc[3] = MFMA16(AP[2], B[7], acc[3]);
          acc[4] = MFMA16(AP[3], B[6], acc[4]);
          acc[5] = MFMA16(AP[3], B[7], acc[5]);
          acc[6] = MFMA16(AH[0], B[6], acc[6]);
          acc[7] = MFMA16(AH[0], B[7], acc[7]);
          SBAR();
          B[6] = Bp[6 << 6]; B[7] = Bp[7 << 6];
          SBAR();
          // k=2: d=4,5
          acc[0] = MFMA16(AP[2], B[4], acc[0]);
          acc[1] = MFMA16(AP[2], B[5], acc[1]);
          acc[2] = MFMA16(AP[3], B[4], acc[2]);
          acc[3] = MFMA16(AP[3], B[5], acc[3]);
          acc[4] = MFMA16(AH[0], B[4], acc[4]);
          acc[5] = MFMA16(AH[0], B[5], acc[5]);
          acc[6] = MFMA16(AH[1], B[4], acc[6]);
          acc[7] = MFMA16(AH[1], B[5], acc[7]);
          SBAR();
          B[4] = Bp[4 << 6]; B[5] = Bp[5 << 6];
          SBAR();
          // k=3: d=2,3 (last AP use)
          acc[0] = MFMA16(AP[3], B[2], acc[0]);
          acc[1] = MFMA16(AP[3], B[3], acc[1]);
          acc[2] = MFMA16(AH[0], B[2], acc[2]);
          acc[3] = MFMA16(AH[0], B[3], acc[3]);
          acc[4] = MFMA16(AH[1], B[2], acc[4]);
          acc[5] = MFMA16(AH[1], B[3], acc[5]);
          acc[6] = MFMA16(AH[2], B[2], acc[6]);
          acc[7] = MFMA16(AH[2], B[3], acc[7]);
          SBAR();
          B[2] = Bp[2 << 6]; B[3] = Bp[3 << 6];
          AP[0] = *(const short8*)(arp);
          AP[1] = *(const short8*)(arp + 32);
          AP[2] = *(const short8*)(arp + 64);
          AP[3] = *(const short8*)(arp + 96);
          SBAR();
          // k=4: d=0,1 (AH only)
          acc[0] = MFMA16(AH[0], B[0], acc[0]);
          acc[1] = MFMA16(AH[0], B[1], acc[1]);
          acc[2] = MFMA16(AH[1], B[0], acc[2]);
          acc[3] = MFMA16(AH[1], B[1], acc[3]);
          acc[4] = MFMA16(AH[2], B[0], acc[4]);
          acc[5] = MFMA16(AH[2], B[1], acc[5]);
          acc[6] = MFMA16(AH[3], B[0], acc[6]);
          acc[7] = MFMA16(AH[3], B[1], acc[7]);
          SBAR();
          B[0] = Bp[0 << 6]; B[1] = Bp[1 << 6];
          SBAR();
        };

        #pragma unroll 1
        for (int q2 = s2; q2 < e2; ++q2) {
          const int q = qlo + q2;
          qstep(q, min(q + 1, 127));
        }
      }

      // apply window for this tile (acc -> facc); norm recomputed in epilogue
      const int Sh = h1 - h0, Sw = w1 - w0;
      const float sig = 0.25f * (float)min(Sh, Sw);
      const float c2 = 0.5f / (sig * sig);
      const float stepy = (float)Sh / (float)(Sh - 1);
      const float stepx = (float)Sw / (float)(Sw - 1);
      float wx[4];
      #pragma unroll
      for (int r = 0; r < 4; ++r) {
        const int x = x0 + (xs << 4) + (hq << 2) + r;
        const float xv = -0.5f * (float)Sw + (float)(x - w0) * stepx;
        wx[r] = (x >= w0 && x < w1) ? __expf(-xv * xv * c2) : 0.0f;
      }
      #pragma unroll
      for (int s = 0; s < 8; ++s) {
        const int y = y0 + (s << 4) + n;
        const float yv = -0.5f * (float)Sh + (float)(y - h0) * stepy;
        const float wy = (y >= h0 && y < h1) ? __expf(-yv * yv * c2) : 0.0f;
        #pragma unroll
        for (int r = 0; r < 4; ++r) facc[s][r] += wy * wx[r] * acc[s][r];
      }
    }
  }

  // epilogue: recompute norm analytically, store out[b,l,x,2047-y]
  f32x4 nacc[8] = {};
  for (int ti = tylo; ti <= tyhi; ++ti) {
    const int h0 = max(0, ti * HS - OV2);
    const int h1 = min(IMH, (ti + 1) * HS + OV2);
    for (int tj = txlo; tj <= txhi; ++tj) {
      const int w0 = max(0, tj * HS - OV2);
      const int w1 = min(IMW, (tj + 1) * HS + OV2);
      const int Sh = h1 - h0, Sw = w1 - w0;
      const float sig = 0.25f * (float)min(Sh, Sw);
      const float c2 = 0.5f / (sig * sig);
      const float stepy = (float)Sh / (float)(Sh - 1);
      const float stepx = (float)Sw / (float)(Sw - 1);
      float wx[4];
      #pragma unroll
      for (int r = 0; r < 4; ++r) {
        const int x = x0 + (xs << 4) + (hq << 2) + r;
        const float xv = -0.5f * (float)Sw + (float)(x - w0) * stepx;
        wx[r] = (x >= w0 && x < w1) ? __expf(-xv * xv * c2) : 0.0f;
      }
      #pragma unroll
      for (int s = 0; s < 8; ++s) {
        const int y = y0 + (s << 4) + n;
        const float yv = -0.5f * (float)Sh + (float)(y - h0) * stepy;
        const float wy = (y >= h0 && y < h1) ? __expf(-yv * yv * c2) : 0.0f;
        #pragma unroll
        for (int r = 0; r < 4; ++r) nacc[s][r] += wy * wx[r];
      }
    }
  }
  #pragma unroll
  for (int s = 0; s < 8; ++s) {
    const int y = y0 + (s << 4) + n;
    #pragma unroll
    for (int r = 0; r < 4; ++r) {
      const int x = x0 + (xs << 4) + (hq << 2) + r;
      out[(((size_t)(b * NL + l) << 11) + x) * IMW + (IMW - 1 - y)] =
          facc[s][r] / fmaxf(nacc[s][r], 1e-12f);
    }
  }
}

extern "C" void kernel_launch(void* const* d_in, const int* in_sizes, int n_in,
                              void* d_out, int out_size, void* d_ws, size_t ws_size,
                              hipStream_t stream) {
  const float* tgt  = (const float*)d_in[0];
  const float* psfs = (const float*)d_in[1];
  ushort* J16 = (ushort*)d_ws;                                       // 16.8 MB
  short8* Bf  = (short8*)((char*)d_ws + (size_t)NB * IMH * IMW * 2); // 62.9 MB
  float* o = (float*)d_out;

  build_J16<<<dim3((NB * IMH * IMW + 255) / 256), 256, 0, stream>>>(tgt, J16);
  build_Bfrag<<<dim3((48 * 128 * NDI * 64 + 255) / 256), 256, 0, stream>>>(
      psfs, (uint4*)Bf);
  conv_mfma<<<dim3(32, 16, NB * NL), 256, 0, stream>>>(J16, Bf, o);
}